// Round 1
// baseline (3511.803 us; speedup 1.0000x reference)
//
#include <hip/hip_runtime.h>
#include <math.h>

// ---------------------------------------------------------------------------
// QuDeepDTA: conv1d+relu+maxpool branches -> Gram -> L2 normalize -> dot
// Round 0: fp32 baseline, VALU-bound by design (no fp32 MFMA on CDNA4).
// ---------------------------------------------------------------------------

template<int V, int L, int K, int NP, int BLOCK>
__global__ __launch_bounds__(BLOCK) void conv_branch_kernel(
    const float* __restrict__ in,    // (B, V, L)
    const float* __restrict__ w,     // (96, V, K)
    const float* __restrict__ bias,  // (96)
    float* __restrict__ feat,        // (B, 192)
    int feat_off)
{
    constexpr int C    = 96;
    constexpr int CT   = 8;            // channels per register tile
    constexpr int LOUT = L - K + 1;    // valid conv output length
    constexpr int NW   = BLOCK / 64;
    static_assert((V * L) % 4 == 0, "float4 staging");
    static_assert(C % CT == 0, "channel tiling");

    __shared__ float s_in[V * L + 64];   // +pad: tail threads read past row end
    __shared__ float s_red[NW * CT];

    const int tid  = threadIdx.x;
    const int b    = blockIdx.x;
    const int wave = tid >> 6;
    const int lane = tid & 63;

    // stage the whole sample into LDS (flat float4 copy, coalesced)
    {
        const float4* gp = reinterpret_cast<const float4*>(in + (size_t)b * (V * L));
        float4* sp = reinterpret_cast<float4*>(s_in);
        constexpr int N4 = V * L / 4;
        for (int i = tid; i < N4; i += BLOCK) sp[i] = gp[i];
    }
    __syncthreads();

    const int l0 = tid * NP;   // this thread's first output position

    for (int cg = 0; cg < C; cg += CT) {
        float acc[CT][NP];
        #pragma unroll
        for (int c = 0; c < CT; ++c)
            #pragma unroll
            for (int p = 0; p < NP; ++p) acc[c][p] = 0.f;

        for (int v = 0; v < V; ++v) {
            // NP consecutive positions share K-tap windows: load NP+K-1 inputs once
            float xin[NP + K - 1];
            const float* sp = s_in + v * L + l0;
            #pragma unroll
            for (int t = 0; t < NP + K - 1; ++t) xin[t] = sp[t];

            #pragma unroll
            for (int c = 0; c < CT; ++c) {
                const float* wp = w + ((cg + c) * V + v) * K;  // wave-uniform -> s_load
                #pragma unroll
                for (int k = 0; k < K; ++k) {
                    const float wk = wp[k];
                    #pragma unroll
                    for (int p = 0; p < NP; ++p)
                        acc[c][p] = fmaf(xin[k + p], wk, acc[c][p]);
                }
            }
        }

        // relu(y+bias) >= 0, so 0 is a valid identity for the max over positions
        #pragma unroll
        for (int c = 0; c < CT; ++c) {
            float m = 0.f;
            const float bb = bias[cg + c];
            #pragma unroll
            for (int p = 0; p < NP; ++p) {
                if (l0 + p < LOUT) m = fmaxf(m, fmaxf(acc[c][p] + bb, 0.f));
            }
            #pragma unroll
            for (int off = 32; off >= 1; off >>= 1)
                m = fmaxf(m, __shfl_xor(m, off, 64));
            if (lane == 0) s_red[wave * CT + c] = m;
        }
        __syncthreads();
        if (tid < CT) {
            float m = s_red[tid];
            #pragma unroll
            for (int wv = 1; wv < NW; ++wv) m = fmaxf(m, s_red[wv * CT + tid]);
            feat[(size_t)b * 192 + feat_off + cg + tid] = m;
        }
        __syncthreads();
    }
}

// 4 samples per block, one wave per sample.
__global__ __launch_bounds__(256) void gram_affinity_kernel(
    const float* __restrict__ feat,   // (B, 192)
    const float* __restrict__ w_aff,  // (1024,)
    const float* __restrict__ b_aff,  // (1,)
    float* __restrict__ out,          // (B,)
    int B)
{
    const int lane = threadIdx.x & 63;
    const int wid  = threadIdx.x >> 6;
    const int b    = blockIdx.x * 4 + wid;

    __shared__ float s_x[4][192];

    if (b < B) {
        const float* fp = feat + (size_t)b * 192;
        for (int i = lane; i < 192; i += 64) s_x[wid][i] = fp[i];
    }
    __syncthreads();   // uniform barrier (guards only the loads above)

    if (b < B) {
        float ssum = 0.f, sdot = 0.f;
        #pragma unroll
        for (int t = 0; t < 16; ++t) {
            const int jk = t * 64 + lane;      // 0..1023
            const int j = jk >> 5, k = jk & 31;
            float g = 0.f;
            #pragma unroll
            for (int i = 0; i < 6; ++i)
                g = fmaf(s_x[wid][i * 32 + j], s_x[wid][i * 32 + k], g);
            ssum = fmaf(g, g, ssum);
            sdot = fmaf(g, w_aff[jk], sdot);
        }
        #pragma unroll
        for (int off = 32; off >= 1; off >>= 1) {
            ssum += __shfl_xor(ssum, off, 64);
            sdot += __shfl_xor(sdot, off, 64);
        }
        if (lane == 0) out[b] = sdot / (sqrtf(ssum) + 1e-12f) + b_aff[0];
    }
}

extern "C" void kernel_launch(void* const* d_in, const int* in_sizes, int n_in,
                              void* d_out, int out_size, void* d_ws, size_t ws_size,
                              hipStream_t stream)
{
    const float* protein = (const float*)d_in[0];  // (B, 25, 1000)
    const float* ligand  = (const float*)d_in[1];  // (B, 64, 100)
    const float* w_pro   = (const float*)d_in[2];  // (96, 25, 8)
    const float* b_pro   = (const float*)d_in[3];  // (96,)
    const float* w_lig   = (const float*)d_in[4];  // (96, 64, 4)
    const float* b_lig   = (const float*)d_in[5];  // (96,)
    const float* w_aff   = (const float*)d_in[6];  // (1024,)
    const float* b_aff   = (const float*)d_in[7];  // (1,)
    float* out = (float*)d_out;
    const int B = out_size;                        // 4096

    float* feat = (float*)d_ws;                    // (B, 192) scratch

    // ligand branch -> feat[:, 0:96]   (concat order: ligand first)
    conv_branch_kernel<64, 100, 4, 1, 128><<<B, 128, 0, stream>>>(
        ligand, w_lig, b_lig, feat, 0);
    // protein branch -> feat[:, 96:192]
    conv_branch_kernel<25, 1000, 8, 4, 256><<<B, 256, 0, stream>>>(
        protein, w_pro, b_pro, feat, 96);
    // Gram + normalize + readout
    gram_affinity_kernel<<<(B + 3) / 4, 256, 0, stream>>>(feat, w_aff, b_aff, out, B);
}

// Round 2
// 370.934 us; speedup vs baseline: 9.4675x; 9.4675x over previous
//
#include <hip/hip_runtime.h>
#include <math.h>

typedef _Float16 f16;
typedef _Float16 f16x8 __attribute__((ext_vector_type(8)));
typedef float f32x16 __attribute__((ext_vector_type(16)));

// ---------------------------------------------------------------------------
// Repack weights (96, V, K) fp32 -> wpack[t][ch][VP] f16, zero-padded v >= V.
// B-fragment for mfma_32x32x16_f16 then reads per-lane contiguous 16B.
// ---------------------------------------------------------------------------
template<int V, int K, int VP>
__global__ void repack_kernel(const float* __restrict__ w, f16* __restrict__ wp) {
    int i = blockIdx.x * 256 + threadIdx.x;
    if (i >= K * 96 * VP) return;
    int v = i % VP, ch = (i / VP) % 96, t = i / (VP * 96);
    float val = (v < V) ? w[(ch * V + v) * K + t] : 0.f;
    wp[i] = (f16)val;
}

// ---------------------------------------------------------------------------
// Conv1d(valid) + bias + relu + maxpool via implicit GEMM on 32x32x16 f16 MFMA.
// M = positions (32-row tiles), N = 96 channels (3 col-waves), K = vpad.
// Taps handled as KT shifted accumulation passes over the same K-dim.
// LDS: s_in[LP][RS] f16, transposed (pos-major) so A-frags are aligned 16B.
// 6 waves: colw = wave%3 (32 channels each), roww = wave/3 (half the tiles).
// ---------------------------------------------------------------------------
template<int V, int L, int KT, int VP, int KSTEPS, int LP, int RS, int NTILES, int LOUT>
__global__ __launch_bounds__(384) void conv_mfma_kernel(
    const float* __restrict__ in,    // (B, V, L) fp32
    const f16*   __restrict__ wp,    // (KT, 96, VP) f16
    const float* __restrict__ bias,  // (96)
    float* __restrict__ feat,        // (B, 192)
    int feat_off)
{
    static_assert((LP * RS * 2) % 16 == 0, "lds float4 zero");
    static_assert(NTILES % 2 == 0, "even tile split");
    __shared__ __align__(16) f16 s_in[LP * RS];

    const int tid  = threadIdx.x;
    const int b    = blockIdx.x;
    const int wave = tid >> 6;
    const int lane = tid & 63;
    const int colw = wave % 3;        // channel group (32 ch)
    const int roww = wave / 3;        // row-tile group
    const int q    = lane >> 5;       // k-subgroup (0..1)
    const int r    = lane & 31;       // A-row / B-col within tile

    // zero all of LDS (covers v-pad columns and row padding)
    {
        float4 z = {0.f, 0.f, 0.f, 0.f};
        float4* sz = (float4*)s_in;
        for (int i = tid; i < LP * RS * 2 / 16; i += 384) sz[i] = z;
    }
    __syncthreads();

    // stage input transposed: s_in[p][v] = in[v][p], fp32 -> f16
    const float* gin = in + (size_t)b * (V * L);
    for (int i = tid; i < V * L; i += 384) {
        int v = i / L, p = i - v * L;
        s_in[p * RS + v] = (f16)gin[i];
    }

    // preload B fragments (weights) into registers: KT x KSTEPS x 16B/lane
    f16x8 bf[KT][KSTEPS];
    #pragma unroll
    for (int t = 0; t < KT; ++t)
        #pragma unroll
        for (int ks = 0; ks < KSTEPS; ++ks)
            bf[t][ks] = *(const f16x8*)(wp + ((t * 96 + colw * 32 + r) * VP + ks * 16 + q * 8));

    __syncthreads();

    float runmax = -3.0e38f;
    for (int it = 0; it < NTILES / 2; ++it) {
        const int tile = roww * (NTILES / 2) + it;
        const int p0   = tile * 32;
        f32x16 acc = {};
        #pragma unroll
        for (int t = 0; t < KT; ++t) {
            int row = p0 + r + t;
            if (row > LP - 1) row = LP - 1;       // clamped row is zero-filled
            const f16* ap = s_in + row * RS + q * 8;
            #pragma unroll
            for (int ks = 0; ks < KSTEPS; ++ks) {
                f16x8 af = *(const f16x8*)(ap + ks * 16);
                acc = __builtin_amdgcn_mfma_f32_32x32x16_f16(af, bf[t][ks], acc, 0, 0, 0);
            }
        }
        // max over this tile's rows; mask rows >= LOUT (their windows are
        // partial sums and can exceed the true max)
        if (p0 + 32 <= LOUT) {
            #pragma unroll
            for (int i = 0; i < 16; ++i) runmax = fmaxf(runmax, acc[i]);
        } else {
            #pragma unroll
            for (int i = 0; i < 16; ++i) {
                int row = (i & 3) + 8 * (i >> 2) + 4 * q;   // C/D row mapping
                if (p0 + row < LOUT) runmax = fmaxf(runmax, acc[i]);
            }
        }
    }

    // col c = colw*32 + r is held by lanes r and r+32: combine halves
    runmax = fmaxf(runmax, __shfl_xor(runmax, 32, 64));

    __syncthreads();                    // s_in no longer needed; reuse as s_red
    float* s_red = (float*)s_in;        // [2][96]
    if (lane < 32) s_red[roww * 96 + colw * 32 + r] = runmax;
    __syncthreads();
    if (tid < 96) {
        float m = fmaxf(s_red[tid], s_red[96 + tid]);
        feat[(size_t)b * 192 + feat_off + tid] = fmaxf(m + bias[tid], 0.f);
    }
}

// ---------------------------------------------------------------------------
// Gram + L2 normalize + readout (unchanged from round 0; 4 samples/block).
// ---------------------------------------------------------------------------
__global__ __launch_bounds__(256) void gram_affinity_kernel(
    const float* __restrict__ feat,   // (B, 192)
    const float* __restrict__ w_aff,  // (1024,)
    const float* __restrict__ b_aff,  // (1,)
    float* __restrict__ out,          // (B,)
    int B)
{
    const int lane = threadIdx.x & 63;
    const int wid  = threadIdx.x >> 6;
    const int b    = blockIdx.x * 4 + wid;

    __shared__ float s_x[4][192];

    if (b < B) {
        const float* fp = feat + (size_t)b * 192;
        for (int i = lane; i < 192; i += 64) s_x[wid][i] = fp[i];
    }
    __syncthreads();

    if (b < B) {
        float ssum = 0.f, sdot = 0.f;
        #pragma unroll
        for (int t = 0; t < 16; ++t) {
            const int jk = t * 64 + lane;      // 0..1023
            const int j = jk >> 5, k = jk & 31;
            float g = 0.f;
            #pragma unroll
            for (int i = 0; i < 6; ++i)
                g = fmaf(s_x[wid][i * 32 + j], s_x[wid][i * 32 + k], g);
            ssum = fmaf(g, g, ssum);
            sdot = fmaf(g, w_aff[jk], sdot);
        }
        #pragma unroll
        for (int off = 32; off >= 1; off >>= 1) {
            ssum += __shfl_xor(ssum, off, 64);
            sdot += __shfl_xor(sdot, off, 64);
        }
        if (lane == 0) out[b] = sdot / (sqrtf(ssum) + 1e-12f) + b_aff[0];
    }
}

extern "C" void kernel_launch(void* const* d_in, const int* in_sizes, int n_in,
                              void* d_out, int out_size, void* d_ws, size_t ws_size,
                              hipStream_t stream)
{
    const float* protein = (const float*)d_in[0];  // (B, 25, 1000)
    const float* ligand  = (const float*)d_in[1];  // (B, 64, 100)
    const float* w_pro   = (const float*)d_in[2];  // (96, 25, 8)
    const float* b_pro   = (const float*)d_in[3];  // (96,)
    const float* w_lig   = (const float*)d_in[4];  // (96, 64, 4)
    const float* b_lig   = (const float*)d_in[5];  // (96,)
    const float* w_aff   = (const float*)d_in[6];  // (1024,)
    const float* b_aff   = (const float*)d_in[7];  // (1,)
    float* out = (float*)d_out;
    const int B = out_size;                        // 4096

    float* feat   = (float*)d_ws;                              // (B,192) f32
    f16*   wpackP = (f16*)((char*)d_ws + (size_t)B * 192 * 4); // 8*96*32 f16
    f16*   wpackL = wpackP + 8 * 96 * 32;                      // 4*96*64 f16

    repack_kernel<25, 8, 32><<<96, 256, 0, stream>>>(w_pro, wpackP);
    repack_kernel<64, 4, 64><<<96, 256, 0, stream>>>(w_lig, wpackL);

    // ligand branch -> feat[:, 0:96]
    conv_mfma_kernel<64, 100, 4, 64, 4, 132, 72, 4, 97>
        <<<B, 384, 0, stream>>>(ligand, wpackL, b_lig, feat, 0);
    // protein branch -> feat[:, 96:192]
    conv_mfma_kernel<25, 1000, 8, 32, 2, 1024, 40, 32, 993>
        <<<B, 384, 0, stream>>>(protein, wpackP, b_pro, feat, 96);

    gram_affinity_kernel<<<(B + 3) / 4, 256, 0, stream>>>(feat, w_aff, b_aff, out, B);
}